// Round 12
// baseline (128.998 us; speedup 1.0000x reference)
//
#include <hip/hip_runtime.h>
#include <hip/hip_bf16.h>

#define NPIX 4096   // 64*64 pixels per batch
#define CCH  64     // channels
#define NB   8      // batch
#define KVBLK 64    // j-tile per pipeline stage (32KB LDS dbuf)

typedef __attribute__((ext_vector_type(8)))  short short8;   // 8 bf16 MFMA A/B frag (32x32x16)
typedef __attribute__((ext_vector_type(4)))  float f32x4;
typedef __attribute__((ext_vector_type(16))) float f32x16;   // 32x32 MFMA C/D frag

#define LOG2E   1.44269504f

// ---------------------------------------------------------------------------
// Kernel 1: fused 1x1-conv projections, LDS-free.
// W-row reads are wave-uniform (oc depends only on wave id + loop const) ->
// scalar/L1-broadcast loads; x column lives in 64 VGPRs (coalesced loads).
//   Q[b][i][oc] = log2e * (W1 x + b1)   (bf16 pixel-major; scaled for exp2)
//   G[b][j][oc] =         (W2 x + b2)   (bf16 pixel-major)
//   K[b][oc][j] =         (W3 x + b3)   (bf16 channel-major)
// ---------------------------------------------------------------------------
__global__ __launch_bounds__(256) void proj_kernel(
    const float* __restrict__ x,
    const float* __restrict__ W1, const float* __restrict__ b1,
    const float* __restrict__ W2, const float* __restrict__ b2,
    const float* __restrict__ W3, const float* __restrict__ b3,
    __hip_bfloat16* __restrict__ Q, __hip_bfloat16* __restrict__ G,
    __hip_bfloat16* __restrict__ K)
{
    const int b  = blockIdx.x >> 6;
    const int i0 = (blockIdx.x & 63) << 6;
    const int p  = threadIdx.x & 63;          // pixel within tile
    const int g  = threadIdx.x >> 6;          // out-channel block [16g, 16g+16)
    const int i  = i0 + p;

    // this thread's x column (coalesced across lanes per c)
    float xv[64];
    #pragma unroll
    for (int c = 0; c < 64; ++c)
        xv[c] = x[(size_t)b * CCH * NPIX + (size_t)c * NPIX + i];

    const float* Ws[3] = {W1, W2, W3};
    const float* bs[3] = {b1, b2, b3};

    #pragma unroll
    for (int m = 0; m < 3; ++m) {
        #pragma unroll
        for (int oo = 0; oo < 16; ++oo) {
            const int oc = g * 16 + oo;
            const float* wrow = Ws[m] + oc * 64;   // uniform -> s_load
            float a = bs[m][oc];
            #pragma unroll
            for (int c = 0; c < 64; ++c)
                a += wrow[c] * xv[c];
            if (m == 0)
                Q[(size_t)b * NPIX * CCH + (size_t)i * CCH + oc] = __float2bfloat16(a * LOG2E);
            else if (m == 1)
                G[(size_t)b * NPIX * CCH + (size_t)i * CCH + oc] = __float2bfloat16(a);
            else
                K[(size_t)b * CCH * NPIX + (size_t)oc * NPIX + i] = __float2bfloat16(a);
        }
    }
}

// ---------------------------------------------------------------------------
// Kernel 2: LDS-staged flash attention, 32x32x16 MFMA, swapped QK^T, KVBLK=64.
// 8 waves x 32 rows (512 threads), <=128 VGPR -> 4 waves/SIMD (R11-proven).
// R12 delta: the whole exp->pack chain is compiler-visible —
//   exp2 = __builtin_amdgcn_exp2f (compiler inserts MFMA->TRANS and
//   TRANS->reader waits), bf16 pair-pack = __float22bfloat162_rn (compiler
//   emits v_cvt_pk_bf16_f32). No fmed3, no s_nop. Only permlane stays asm
//   (VALU-in/VALU-out boundary, R3-R11-proven safe).
// 32x32x16 bf16 layouts (m74/m101-verified C/D; A/B contiguous-8k):
//   A: row=lane&31, k=8*(lane>>5)+t     B: col=lane&31, k=8*(lane>>5)+t
//   C/D: col=lane&31, row=(r&3)+8*(r>>2)+4*(lane>>5)
// LDS per buf: G[64 rows][128B] swz ^(row&7)<<4, K[64 c-rows][128B] same.
// ---------------------------------------------------------------------------
__device__ __forceinline__ void gload_lds16(const void* g, void* l) {
    __builtin_amdgcn_global_load_lds(
        (const __attribute__((address_space(1))) unsigned int*)g,
        (__attribute__((address_space(3))) unsigned int*)l, 16, 0, 0);
}
__device__ __forceinline__ unsigned int pack_bf16(float lo, float hi) {
    union { __hip_bfloat162 h; unsigned int u; } w;
    w.h = __float22bfloat162_rn(make_float2(lo, hi));
    return w.u;
}

__global__ __launch_bounds__(512, 4) void attn_kernel(
    const __hip_bfloat16* __restrict__ Qg, const __hip_bfloat16* __restrict__ Gg,
    const __hip_bfloat16* __restrict__ Kg,
    __hip_bfloat16* __restrict__ Opart, float* __restrict__ Lpart, int split)
{
    __shared__ char lds[2][16384];      // [buf][ G 8KB | K 8KB ], XOR-swizzled

    const int blk   = blockIdx.x;
    const int per_b = 16 * split;
    const int b     = blk / per_b;
    const int rem   = blk - b * per_b;
    const int itile = rem / split;
    const int sp    = rem - itile * split;
    const int tid   = threadIdx.x;
    const int wave  = tid >> 6;                   // 0..7
    const int lane  = tid & 63;
    const int l32   = lane & 31;
    const int hi    = lane >> 5;
    const int i0w   = itile * 256 + wave * 32;    // wave's first of 32 rows
    const int jcnt  = NPIX / split;
    const int jlo   = sp * jcnt;
    const int niter = jcnt / KVBLK;

    const short* Qb = (const short*)Qg + (size_t)b * NPIX * CCH;
    const char*  Gb = (const char*)(Gg + (size_t)b * NPIX * CCH);
    const char*  Kb = (const char*)(Kg + (size_t)b * CCH * NPIX);

    // Q B-frags: q[ks] -> Q[i0w+l32][16ks+8hi+t]
    short8 q[4];
    #pragma unroll
    for (int ks = 0; ks < 4; ++ks)
        q[ks] = *(const short8*)(Qb + (size_t)(i0w + l32) * CCH + ks * 16 + hi * 8);

    // hoisted per-lane LDS read bases; per-read addr = base ^ (slot<<4), slot=2ks+hi
    int gbase[2], kbase[2];
    #pragma unroll
    for (int jb = 0; jb < 2; ++jb)
        gbase[jb] = (jb * 32 + l32) * 128 + ((l32 & 7) << 4);
    #pragma unroll
    for (int cb = 0; cb < 2; ++cb)
        kbase[cb] = 8192 + (cb * 32 + l32) * 128 + ((l32 & 7) << 4);

    // hoisted per-lane staging source pointers (512 threads cover 8KB per half)
    const int srow = tid >> 3, scolb = (tid & 7) * 16;
    const char* gsrc = Gb + (size_t)(jlo + srow) * 128 + (scolb ^ ((srow & 7) << 4));
    const char* ksrc = Kb + (size_t)srow * 8192 + (size_t)jlo * 2 + (scolb ^ ((srow & 7) << 4));

    f32x16 zacc;
    #pragma unroll
    for (int r = 0; r < 16; ++r) zacc[r] = 0.f;

    f32x16 o[2];                         // [cb] O^T accumulators (32 rows x 64 ch)
    #pragma unroll
    for (int cb = 0; cb < 2; ++cb)
        #pragma unroll
        for (int r = 0; r < 16; ++r) o[cb][r] = 0.f;
    float ps = 0.f;                      // per-lane denominator partial (i = lane&31)

    auto STAGE = [&](int buf, int tt) {
        gload_lds16(gsrc + tt * (KVBLK * 128), lds[buf] + wave * 1024);
        gload_lds16(ksrc + tt * (KVBLK * 2),  lds[buf] + 8192 + wave * 1024);
    };

    STAGE(0, 0);
    __syncthreads();

    for (int t = 0; t < niter; ++t) {
        const int cur = t & 1;
        STAGE(cur ^ 1, (t + 1 < niter) ? t + 1 : 0);   // uniform (tail re-stages tile 0)
        const char* L = lds[cur];

        #pragma unroll
        for (int jb = 0; jb < 2; ++jb) {
            short8 ga[4];
            #pragma unroll
            for (int ks = 0; ks < 4; ++ks)
                ga[ks] = *(const short8*)(L + (gbase[jb] ^ ((2 * ks + hi) << 4)));

            __builtin_amdgcn_s_setprio(1);
            f32x16 acc = __builtin_amdgcn_mfma_f32_32x32x16_bf16(ga[0], q[0], zacc, 0, 0, 0);
            acc = __builtin_amdgcn_mfma_f32_32x32x16_bf16(ga[1], q[1], acc, 0, 0, 0);
            acc = __builtin_amdgcn_mfma_f32_32x32x16_bf16(ga[2], q[2], acc, 0, 0, 0);
            acc = __builtin_amdgcn_mfma_f32_32x32x16_bf16(ga[3], q[3], acc, 0, 0, 0);
            __builtin_amdgcn_s_setprio(0);

            float p[16];
            #pragma unroll
            for (int r = 0; r < 16; ++r) {
                p[r] = __builtin_amdgcn_exp2f(acc[r]);
                ps += p[r];
            }
            // pack: p[r] holds j_local=(r&3)+8*(r>>2)+4hi; PV B-frag needs
            // lane(hi) to hold j=16kk'+8hi+t. cvt_pk pairs + permlane32_swap (T12).
            short8 pf[2];
            #pragma unroll
            for (int kk = 0; kk < 2; ++kk) {
                unsigned int x0 = pack_bf16(p[8 * kk + 0], p[8 * kk + 1]);
                unsigned int x1 = pack_bf16(p[8 * kk + 2], p[8 * kk + 3]);
                unsigned int y0 = pack_bf16(p[8 * kk + 4], p[8 * kk + 5]);
                unsigned int y1 = pack_bf16(p[8 * kk + 6], p[8 * kk + 7]);
                asm("v_permlane32_swap_b32 %0, %1" : "+v"(x0), "+v"(y0));
                asm("v_permlane32_swap_b32 %0, %1" : "+v"(x1), "+v"(y1));
                union { unsigned int u[4]; short8 v; } w;
                w.u[0] = x0; w.u[1] = x1; w.u[2] = y0; w.u[3] = y1;
                pf[kk] = w.v;
            }

            // PV for this jb's two k-slices (ksg = 2jb+kk)
            __builtin_amdgcn_s_setprio(1);
            #pragma unroll
            for (int kk = 0; kk < 2; ++kk) {
                const int ksg = 2 * jb + kk;
                const short8 ka0 = *(const short8*)(L + (kbase[0] ^ ((2 * ksg + hi) << 4)));
                const short8 ka1 = *(const short8*)(L + (kbase[1] ^ ((2 * ksg + hi) << 4)));
                o[0] = __builtin_amdgcn_mfma_f32_32x32x16_bf16(ka0, pf[kk], o[0], 0, 0, 0);
                o[1] = __builtin_amdgcn_mfma_f32_32x32x16_bf16(ka1, pf[kk], o[1], 0, 0, 0);
            }
            __builtin_amdgcn_s_setprio(0);
        }
        __syncthreads();   // drains staging vmcnt + all waves done reading cur
    }

    // epilogue: O^T is channel-major -> coalesced bf16 stores
    const size_t pb = (size_t)(b * split + sp);
    #pragma unroll
    for (int cb = 0; cb < 2; ++cb)
        #pragma unroll
        for (int r = 0; r < 16; ++r) {
            const int c = cb * 32 + (r & 3) + 8 * (r >> 2) + 4 * hi;
            const int i = i0w + l32;
            Opart[(pb * CCH + c) * NPIX + i] = __float2bfloat16(o[cb][r]);
        }
    // combine hi-halves of the per-lane denominator partial
    ps += __shfl_xor(ps, 32);
    if (lane < 32)
        Lpart[pb * NPIX + i0w + l32] = ps;
}

// ---------------------------------------------------------------------------
// Kernel 3: combine split partials: out[b][c][i] = sum_sp O / sum_sp L + x
// (Opart bf16, channel-major like x/out: no transpose needed.)
// ---------------------------------------------------------------------------
__global__ __launch_bounds__(256) void combine_kernel(
    const __hip_bfloat16* __restrict__ Opart, const float* __restrict__ Lpart,
    const float* __restrict__ x, float* __restrict__ out, int split)
{
    const int b = blockIdx.x >> 6, c = blockIdx.x & 63;
    #pragma unroll
    for (int chunk = 0; chunk < 2; ++chunk) {
        const int i = chunk * 2048 + threadIdx.x * 8;
        float acc[8] = {0,0,0,0,0,0,0,0};
        float Ls[8]  = {0,0,0,0,0,0,0,0};
        for (int s = 0; s < split; ++s) {
            const size_t pb = (size_t)(b * split + s);
            const short8 ov = *(const short8*)((const short*)Opart + (pb * CCH + c) * NPIX + i);
            const f32x4 l0 = *(const f32x4*)&Lpart[pb * NPIX + i];
            const f32x4 l1 = *(const f32x4*)&Lpart[pb * NPIX + i + 4];
            #pragma unroll
            for (int t = 0; t < 8; ++t) {
                union { unsigned int u; float f; } cv;
                cv.u = ((unsigned int)(unsigned short)ov[t]) << 16;
                acc[t] += cv.f;
                Ls[t]  += (t < 4) ? l0[t] : l1[t - 4];
            }
        }
        const size_t idx = ((size_t)b * CCH + c) * NPIX + i;
        const f32x4 xv0 = *(const f32x4*)&x[idx];
        const f32x4 xv1 = *(const f32x4*)&x[idx + 4];
        f32x4 r0, r1;
        #pragma unroll
        for (int t = 0; t < 4; ++t) {
            r0[t] = acc[t] / Ls[t] + xv0[t];
            r1[t] = acc[t + 4] / Ls[t + 4] + xv1[t];
        }
        *(f32x4*)&out[idx]     = r0;
        *(f32x4*)&out[idx + 4] = r1;
    }
}

extern "C" void kernel_launch(void* const* d_in, const int* in_sizes, int n_in,
                              void* d_out, int out_size, void* d_ws, size_t ws_size,
                              hipStream_t stream) {
    const float* x  = (const float*)d_in[0];
    const float* W1 = (const float*)d_in[1];
    const float* b1 = (const float*)d_in[2];
    const float* W2 = (const float*)d_in[3];
    const float* b2 = (const float*)d_in[4];
    const float* W3 = (const float*)d_in[5];
    const float* b3 = (const float*)d_in[6];
    float* out = (float*)d_out;

    char* ws = (char*)d_ws;
    const size_t planeB = (size_t)NB * NPIX * CCH * sizeof(__hip_bfloat16); // 4 MB
    __hip_bfloat16* Q = (__hip_bfloat16*)(ws);
    __hip_bfloat16* G = (__hip_bfloat16*)(ws + planeB);
    __hip_bfloat16* K = (__hip_bfloat16*)(ws + 2 * planeB);

    const size_t base   = 3 * planeB;                               // 12 MB
    const size_t oPlane = planeB;                                   // 4 MB per split (bf16)
    const size_t lPlane = (size_t)NB * NPIX * sizeof(float);        // 128 KB per split

    // prefer split=8 (1024 blocks); fall back if ws is tight
    int split = 8;
    while (split > 1 && base + (size_t)split * (oPlane + lPlane) > ws_size)
        split >>= 1;

    __hip_bfloat16* Opart = (__hip_bfloat16*)(ws + base);
    float* Lpart = (float*)(ws + base + (size_t)split * oPlane);

    proj_kernel<<<dim3(NB * 64), dim3(256), 0, stream>>>(x, W1, b1, W2, b2, W3, b3, Q, G, K);
    attn_kernel<<<dim3(NB * 16 * split), dim3(512), 0, stream>>>(Q, G, K, Opart, Lpart, split);
    combine_kernel<<<dim3(NB * CCH), dim3(256), 0, stream>>>(Opart, Lpart, x, out, split);
}

// Round 13
// 86.128 us; speedup vs baseline: 1.4978x; 1.4978x over previous
//
#include <hip/hip_runtime.h>
#include <hip/hip_bf16.h>

#define NPIX 4096   // 64*64 pixels per batch
#define CCH  64     // channels
#define NB   8      // batch
#define KVBLK 64    // j-tile per pipeline stage (32KB LDS dbuf)

typedef __attribute__((ext_vector_type(8)))  short short8;   // 8 bf16 MFMA A/B frag (32x32x16)
typedef __attribute__((ext_vector_type(4)))  float f32x4;
typedef __attribute__((ext_vector_type(16))) float f32x16;   // 32x32 MFMA C/D frag

#define LOG2E   1.44269504f

// ---------------------------------------------------------------------------
// Kernel 1: fused 1x1-conv projections (R0-R11 proven LDS version).
//   Q[b][i][oc] = log2e * (W1 x + b1)   (bf16 pixel-major; scaled for exp2)
//   G[b][j][oc] =         (W2 x + b2)   (bf16 pixel-major)
//   K[b][oc][j] =         (W3 x + b3)   (bf16 channel-major)
// R12's "LDS-free" variant regressed 5x: compiler can't prove W-row
// uniformity -> 3072 broadcast vector loads/thread. Reverted.
// ---------------------------------------------------------------------------
__global__ __launch_bounds__(256) void proj_kernel(
    const float* __restrict__ x,
    const float* __restrict__ W1, const float* __restrict__ b1,
    const float* __restrict__ W2, const float* __restrict__ b2,
    const float* __restrict__ W3, const float* __restrict__ b3,
    __hip_bfloat16* __restrict__ Q, __hip_bfloat16* __restrict__ G,
    __hip_bfloat16* __restrict__ K)
{
    const int b  = blockIdx.x >> 6;
    const int i0 = (blockIdx.x & 63) << 6;

    __shared__ float xs[64][65];
    __shared__ float Wt[3][64][68];

    for (int e = threadIdx.x; e < 4096; e += 256) {
        const int c = e >> 6, p = e & 63;
        xs[c][p] = x[(size_t)b * CCH * NPIX + (size_t)c * NPIX + i0 + p];
        Wt[0][e & 63][e >> 6] = W1[e];
        Wt[1][e & 63][e >> 6] = W2[e];
        Wt[2][e & 63][e >> 6] = W3[e];
    }
    __syncthreads();

    const int p = threadIdx.x & 63;
    const int g = threadIdx.x >> 6;

    float acc0[16], acc1[16], acc2[16];
    #pragma unroll
    for (int oo = 0; oo < 16; ++oo) {
        acc0[oo] = b1[g * 16 + oo];
        acc1[oo] = b2[g * 16 + oo];
        acc2[oo] = b3[g * 16 + oo];
    }

    for (int c = 0; c < 64; ++c) {
        const float xv = xs[c][p];
        const f32x4* w0 = (const f32x4*)&Wt[0][c][g * 16];
        const f32x4* w1 = (const f32x4*)&Wt[1][c][g * 16];
        const f32x4* w2 = (const f32x4*)&Wt[2][c][g * 16];
        #pragma unroll
        for (int q = 0; q < 4; ++q) {
            const f32x4 a = w0[q], bb = w1[q], cc = w2[q];
            #pragma unroll
            for (int j = 0; j < 4; ++j) {
                acc0[q * 4 + j] += a[j] * xv;
                acc1[q * 4 + j] += bb[j] * xv;
                acc2[q * 4 + j] += cc[j] * xv;
            }
        }
    }

    const int i = i0 + p;
    #pragma unroll
    for (int oo = 0; oo < 16; ++oo) {
        const int oc = g * 16 + oo;
        Q[(size_t)b * NPIX * CCH + (size_t)i * CCH + oc] = __float2bfloat16(acc0[oo] * LOG2E);
        G[(size_t)b * NPIX * CCH + (size_t)i * CCH + oc] = __float2bfloat16(acc1[oo]);
        K[(size_t)b * CCH * NPIX + (size_t)oc * NPIX + i] = __float2bfloat16(acc2[oo]);
    }
}

// ---------------------------------------------------------------------------
// Kernel 2: LDS-staged flash attention, 32x32x16 MFMA, swapped QK^T, KVBLK=64.
// 8 waves x 32 rows (512 threads), <=128 VGPR -> 4 waves/SIMD (R11-proven).
// R12-validated: compiler-visible exp->pack chain (builtin exp2f +
// __float22bfloat162_rn); only permlane stays asm. Byte-identical to R12.
// 32x32x16 bf16 layouts (m74/m101-verified C/D; A/B contiguous-8k):
//   A: row=lane&31, k=8*(lane>>5)+t     B: col=lane&31, k=8*(lane>>5)+t
//   C/D: col=lane&31, row=(r&3)+8*(r>>2)+4*(lane>>5)
// LDS per buf: G[64 rows][128B] swz ^(row&7)<<4, K[64 c-rows][128B] same.
// ---------------------------------------------------------------------------
__device__ __forceinline__ void gload_lds16(const void* g, void* l) {
    __builtin_amdgcn_global_load_lds(
        (const __attribute__((address_space(1))) unsigned int*)g,
        (__attribute__((address_space(3))) unsigned int*)l, 16, 0, 0);
}
__device__ __forceinline__ unsigned int pack_bf16(float lo, float hi) {
    union { __hip_bfloat162 h; unsigned int u; } w;
    w.h = __float22bfloat162_rn(make_float2(lo, hi));
    return w.u;
}

__global__ __launch_bounds__(512, 4) void attn_kernel(
    const __hip_bfloat16* __restrict__ Qg, const __hip_bfloat16* __restrict__ Gg,
    const __hip_bfloat16* __restrict__ Kg,
    __hip_bfloat16* __restrict__ Opart, float* __restrict__ Lpart, int split)
{
    __shared__ char lds[2][16384];      // [buf][ G 8KB | K 8KB ], XOR-swizzled

    const int blk   = blockIdx.x;
    const int per_b = 16 * split;
    const int b     = blk / per_b;
    const int rem   = blk - b * per_b;
    const int itile = rem / split;
    const int sp    = rem - itile * split;
    const int tid   = threadIdx.x;
    const int wave  = tid >> 6;                   // 0..7
    const int lane  = tid & 63;
    const int l32   = lane & 31;
    const int hi    = lane >> 5;
    const int i0w   = itile * 256 + wave * 32;    // wave's first of 32 rows
    const int jcnt  = NPIX / split;
    const int jlo   = sp * jcnt;
    const int niter = jcnt / KVBLK;

    const short* Qb = (const short*)Qg + (size_t)b * NPIX * CCH;
    const char*  Gb = (const char*)(Gg + (size_t)b * NPIX * CCH);
    const char*  Kb = (const char*)(Kg + (size_t)b * CCH * NPIX);

    // Q B-frags: q[ks] -> Q[i0w+l32][16ks+8hi+t]
    short8 q[4];
    #pragma unroll
    for (int ks = 0; ks < 4; ++ks)
        q[ks] = *(const short8*)(Qb + (size_t)(i0w + l32) * CCH + ks * 16 + hi * 8);

    // hoisted per-lane LDS read bases; per-read addr = base ^ (slot<<4), slot=2ks+hi
    int gbase[2], kbase[2];
    #pragma unroll
    for (int jb = 0; jb < 2; ++jb)
        gbase[jb] = (jb * 32 + l32) * 128 + ((l32 & 7) << 4);
    #pragma unroll
    for (int cb = 0; cb < 2; ++cb)
        kbase[cb] = 8192 + (cb * 32 + l32) * 128 + ((l32 & 7) << 4);

    // hoisted per-lane staging source pointers (512 threads cover 8KB per half)
    const int srow = tid >> 3, scolb = (tid & 7) * 16;
    const char* gsrc = Gb + (size_t)(jlo + srow) * 128 + (scolb ^ ((srow & 7) << 4));
    const char* ksrc = Kb + (size_t)srow * 8192 + (size_t)jlo * 2 + (scolb ^ ((srow & 7) << 4));

    f32x16 zacc;
    #pragma unroll
    for (int r = 0; r < 16; ++r) zacc[r] = 0.f;

    f32x16 o[2];                         // [cb] O^T accumulators (32 rows x 64 ch)
    #pragma unroll
    for (int cb = 0; cb < 2; ++cb)
        #pragma unroll
        for (int r = 0; r < 16; ++r) o[cb][r] = 0.f;
    float ps = 0.f;                      // per-lane denominator partial (i = lane&31)

    auto STAGE = [&](int buf, int tt) {
        gload_lds16(gsrc + tt * (KVBLK * 128), lds[buf] + wave * 1024);
        gload_lds16(ksrc + tt * (KVBLK * 2),  lds[buf] + 8192 + wave * 1024);
    };

    STAGE(0, 0);
    __syncthreads();

    for (int t = 0; t < niter; ++t) {
        const int cur = t & 1;
        STAGE(cur ^ 1, (t + 1 < niter) ? t + 1 : 0);   // uniform (tail re-stages tile 0)
        const char* L = lds[cur];

        #pragma unroll
        for (int jb = 0; jb < 2; ++jb) {
            short8 ga[4];
            #pragma unroll
            for (int ks = 0; ks < 4; ++ks)
                ga[ks] = *(const short8*)(L + (gbase[jb] ^ ((2 * ks + hi) << 4)));

            __builtin_amdgcn_s_setprio(1);
            f32x16 acc = __builtin_amdgcn_mfma_f32_32x32x16_bf16(ga[0], q[0], zacc, 0, 0, 0);
            acc = __builtin_amdgcn_mfma_f32_32x32x16_bf16(ga[1], q[1], acc, 0, 0, 0);
            acc = __builtin_amdgcn_mfma_f32_32x32x16_bf16(ga[2], q[2], acc, 0, 0, 0);
            acc = __builtin_amdgcn_mfma_f32_32x32x16_bf16(ga[3], q[3], acc, 0, 0, 0);
            __builtin_amdgcn_s_setprio(0);

            float p[16];
            #pragma unroll
            for (int r = 0; r < 16; ++r) {
                p[r] = __builtin_amdgcn_exp2f(acc[r]);
                ps += p[r];
            }
            // pack: p[r] holds j_local=(r&3)+8*(r>>2)+4hi; PV B-frag needs
            // lane(hi) to hold j=16kk'+8hi+t. cvt_pk pairs + permlane32_swap (T12).
            short8 pf[2];
            #pragma unroll
            for (int kk = 0; kk < 2; ++kk) {
                unsigned int x0 = pack_bf16(p[8 * kk + 0], p[8 * kk + 1]);
                unsigned int x1 = pack_bf16(p[8 * kk + 2], p[8 * kk + 3]);
                unsigned int y0 = pack_bf16(p[8 * kk + 4], p[8 * kk + 5]);
                unsigned int y1 = pack_bf16(p[8 * kk + 6], p[8 * kk + 7]);
                asm("v_permlane32_swap_b32 %0, %1" : "+v"(x0), "+v"(y0));
                asm("v_permlane32_swap_b32 %0, %1" : "+v"(x1), "+v"(y1));
                union { unsigned int u[4]; short8 v; } w;
                w.u[0] = x0; w.u[1] = x1; w.u[2] = y0; w.u[3] = y1;
                pf[kk] = w.v;
            }

            // PV for this jb's two k-slices (ksg = 2jb+kk)
            __builtin_amdgcn_s_setprio(1);
            #pragma unroll
            for (int kk = 0; kk < 2; ++kk) {
                const int ksg = 2 * jb + kk;
                const short8 ka0 = *(const short8*)(L + (kbase[0] ^ ((2 * ksg + hi) << 4)));
                const short8 ka1 = *(const short8*)(L + (kbase[1] ^ ((2 * ksg + hi) << 4)));
                o[0] = __builtin_amdgcn_mfma_f32_32x32x16_bf16(ka0, pf[kk], o[0], 0, 0, 0);
                o[1] = __builtin_amdgcn_mfma_f32_32x32x16_bf16(ka1, pf[kk], o[1], 0, 0, 0);
            }
            __builtin_amdgcn_s_setprio(0);
        }
        __syncthreads();   // drains staging vmcnt + all waves done reading cur
    }

    // epilogue: O^T is channel-major -> coalesced bf16 stores
    const size_t pb = (size_t)(b * split + sp);
    #pragma unroll
    for (int cb = 0; cb < 2; ++cb)
        #pragma unroll
        for (int r = 0; r < 16; ++r) {
            const int c = cb * 32 + (r & 3) + 8 * (r >> 2) + 4 * hi;
            const int i = i0w + l32;
            Opart[(pb * CCH + c) * NPIX + i] = __float2bfloat16(o[cb][r]);
        }
    // combine hi-halves of the per-lane denominator partial
    ps += __shfl_xor(ps, 32);
    if (lane < 32)
        Lpart[pb * NPIX + i0w + l32] = ps;
}

// ---------------------------------------------------------------------------
// Kernel 3: combine split partials: out[b][c][i] = sum_sp O / sum_sp L + x
// (Opart bf16, channel-major like x/out: no transpose needed.)
// ---------------------------------------------------------------------------
__global__ __launch_bounds__(256) void combine_kernel(
    const __hip_bfloat16* __restrict__ Opart, const float* __restrict__ Lpart,
    const float* __restrict__ x, float* __restrict__ out, int split)
{
    const int b = blockIdx.x >> 6, c = blockIdx.x & 63;
    #pragma unroll
    for (int chunk = 0; chunk < 2; ++chunk) {
        const int i = chunk * 2048 + threadIdx.x * 8;
        float acc[8] = {0,0,0,0,0,0,0,0};
        float Ls[8]  = {0,0,0,0,0,0,0,0};
        for (int s = 0; s < split; ++s) {
            const size_t pb = (size_t)(b * split + s);
            const short8 ov = *(const short8*)((const short*)Opart + (pb * CCH + c) * NPIX + i);
            const f32x4 l0 = *(const f32x4*)&Lpart[pb * NPIX + i];
            const f32x4 l1 = *(const f32x4*)&Lpart[pb * NPIX + i + 4];
            #pragma unroll
            for (int t = 0; t < 8; ++t) {
                union { unsigned int u; float f; } cv;
                cv.u = ((unsigned int)(unsigned short)ov[t]) << 16;
                acc[t] += cv.f;
                Ls[t]  += (t < 4) ? l0[t] : l1[t - 4];
            }
        }
        const size_t idx = ((size_t)b * CCH + c) * NPIX + i;
        const f32x4 xv0 = *(const f32x4*)&x[idx];
        const f32x4 xv1 = *(const f32x4*)&x[idx + 4];
        f32x4 r0, r1;
        #pragma unroll
        for (int t = 0; t < 4; ++t) {
            r0[t] = acc[t] / Ls[t] + xv0[t];
            r1[t] = acc[t + 4] / Ls[t + 4] + xv1[t];
        }
        *(f32x4*)&out[idx]     = r0;
        *(f32x4*)&out[idx + 4] = r1;
    }
}

extern "C" void kernel_launch(void* const* d_in, const int* in_sizes, int n_in,
                              void* d_out, int out_size, void* d_ws, size_t ws_size,
                              hipStream_t stream) {
    const float* x  = (const float*)d_in[0];
    const float* W1 = (const float*)d_in[1];
    const float* b1 = (const float*)d_in[2];
    const float* W2 = (const float*)d_in[3];
    const float* b2 = (const float*)d_in[4];
    const float* W3 = (const float*)d_in[5];
    const float* b3 = (const float*)d_in[6];
    float* out = (float*)d_out;

    char* ws = (char*)d_ws;
    const size_t planeB = (size_t)NB * NPIX * CCH * sizeof(__hip_bfloat16); // 4 MB
    __hip_bfloat16* Q = (__hip_bfloat16*)(ws);
    __hip_bfloat16* G = (__hip_bfloat16*)(ws + planeB);
    __hip_bfloat16* K = (__hip_bfloat16*)(ws + 2 * planeB);

    const size_t base   = 3 * planeB;                               // 12 MB
    const size_t oPlane = planeB;                                   // 4 MB per split (bf16)
    const size_t lPlane = (size_t)NB * NPIX * sizeof(float);        // 128 KB per split

    // prefer split=8 (1024 blocks); fall back if ws is tight
    int split = 8;
    while (split > 1 && base + (size_t)split * (oPlane + lPlane) > ws_size)
        split >>= 1;

    __hip_bfloat16* Opart = (__hip_bfloat16*)(ws + base);
    float* Lpart = (float*)(ws + base + (size_t)split * oPlane);

    proj_kernel<<<dim3(NB * 64), dim3(256), 0, stream>>>(x, W1, b1, W2, b2, W3, b3, Q, G, K);
    attn_kernel<<<dim3(NB * 16 * split), dim3(512), 0, stream>>>(Q, G, K, Opart, Lpart, split);
    combine_kernel<<<dim3(NB * CCH), dim3(256), 0, stream>>>(Opart, Lpart, x, out, split);
}

// Round 14
// 82.090 us; speedup vs baseline: 1.5714x; 1.0492x over previous
//
#include <hip/hip_runtime.h>
#include <hip/hip_bf16.h>

#define NPIX 4096   // 64*64 pixels per batch
#define CCH  64     // channels
#define NB   8      // batch
#define KVBLK 64    // j-tile per pipeline stage (32KB LDS dbuf)

typedef __attribute__((ext_vector_type(8)))  short short8;   // 8 bf16 MFMA A/B frag (32x32x16)
typedef __attribute__((ext_vector_type(4)))  float f32x4;
typedef __attribute__((ext_vector_type(16))) float f32x16;   // 32x32 MFMA C/D frag

#define LOG2E   1.44269504f

// ---------------------------------------------------------------------------
// Kernel 1: fused 1x1-conv projections, m-split across blocks (R14).
// grid = NB*64*3; block handles ONE matrix m for one 64-pixel tile.
// Per-thread LDS issues drop 832 -> 320 (the R13 all-m version was
// LDS-issue-bound at ~11us). x re-read 3x from HBM but L2/L3-resident.
//   m=0: Q[b][i][oc] = log2e * (W1 x + b1)   (bf16 pixel-major)
//   m=1: G[b][j][oc] =         (W2 x + b2)   (bf16 pixel-major)
//   m=2: K[b][oc][j] =         (W3 x + b3)   (bf16 channel-major)
// ---------------------------------------------------------------------------
__global__ __launch_bounds__(256) void proj_kernel(
    const float* __restrict__ x,
    const float* __restrict__ W1, const float* __restrict__ b1,
    const float* __restrict__ W2, const float* __restrict__ b2,
    const float* __restrict__ W3, const float* __restrict__ b3,
    __hip_bfloat16* __restrict__ Q, __hip_bfloat16* __restrict__ G,
    __hip_bfloat16* __restrict__ K)
{
    const int m    = blockIdx.x % 3;
    const int tile = blockIdx.x / 3;
    const int b    = tile >> 6;
    const int i0   = (tile & 63) << 6;

    const float* W  = (m == 0) ? W1 : (m == 1) ? W2 : W3;
    const float* bv = (m == 0) ? b1 : (m == 1) ? b2 : b3;

    __shared__ float xs[64][65];      // xs[c][p]
    __shared__ float Wt[64][68];      // Wt[c][oc], rows 16B-aligned

    for (int e = threadIdx.x; e < 4096; e += 256) {
        const int c = e >> 6, p = e & 63;
        xs[c][p] = x[(size_t)b * CCH * NPIX + (size_t)c * NPIX + i0 + p];
        Wt[e & 63][e >> 6] = W[e];    // coalesced read of W[oc][c], transposed store
    }
    __syncthreads();

    const int p = threadIdx.x & 63;   // pixel within tile
    const int g = threadIdx.x >> 6;   // out-channel block [16g, 16g+16)

    float acc[16];
    #pragma unroll
    for (int oo = 0; oo < 16; ++oo) acc[oo] = bv[g * 16 + oo];

    for (int c = 0; c < 64; ++c) {
        const float xv = xs[c][p];
        const f32x4* w = (const f32x4*)&Wt[c][g * 16];
        #pragma unroll
        for (int qq = 0; qq < 4; ++qq) {
            const f32x4 a = w[qq];
            #pragma unroll
            for (int j = 0; j < 4; ++j)
                acc[qq * 4 + j] += a[j] * xv;
        }
    }

    const int i = i0 + p;
    if (m == 0) {
        #pragma unroll
        for (int oo = 0; oo < 16; ++oo)
            Q[(size_t)b * NPIX * CCH + (size_t)i * CCH + g * 16 + oo] =
                __float2bfloat16(acc[oo] * LOG2E);
    } else if (m == 1) {
        #pragma unroll
        for (int oo = 0; oo < 16; ++oo)
            G[(size_t)b * NPIX * CCH + (size_t)i * CCH + g * 16 + oo] =
                __float2bfloat16(acc[oo]);
    } else {
        #pragma unroll
        for (int oo = 0; oo < 16; ++oo)
            K[(size_t)b * CCH * NPIX + (size_t)(g * 16 + oo) * NPIX + i] =
                __float2bfloat16(acc[oo]);
    }
}

// ---------------------------------------------------------------------------
// Kernel 2: LDS-staged flash attention, 32x32x16 MFMA, swapped QK^T, KVBLK=64.
// 8 waves x 32 rows (512 threads), <=128 VGPR -> 4 waves/SIMD (R11-proven).
// Compiler-visible exp->pack chain (builtin exp2f + __float22bfloat162_rn);
// only permlane stays asm. Byte-identical to R13.
// 32x32x16 bf16 layouts (m74/m101-verified C/D; A/B contiguous-8k):
//   A: row=lane&31, k=8*(lane>>5)+t     B: col=lane&31, k=8*(lane>>5)+t
//   C/D: col=lane&31, row=(r&3)+8*(r>>2)+4*(lane>>5)
// LDS per buf: G[64 rows][128B] swz ^(row&7)<<4, K[64 c-rows][128B] same.
// ---------------------------------------------------------------------------
__device__ __forceinline__ void gload_lds16(const void* g, void* l) {
    __builtin_amdgcn_global_load_lds(
        (const __attribute__((address_space(1))) unsigned int*)g,
        (__attribute__((address_space(3))) unsigned int*)l, 16, 0, 0);
}
__device__ __forceinline__ unsigned int pack_bf16(float lo, float hi) {
    union { __hip_bfloat162 h; unsigned int u; } w;
    w.h = __float22bfloat162_rn(make_float2(lo, hi));
    return w.u;
}

__global__ __launch_bounds__(512, 4) void attn_kernel(
    const __hip_bfloat16* __restrict__ Qg, const __hip_bfloat16* __restrict__ Gg,
    const __hip_bfloat16* __restrict__ Kg,
    __hip_bfloat16* __restrict__ Opart, float* __restrict__ Lpart, int split)
{
    __shared__ char lds[2][16384];      // [buf][ G 8KB | K 8KB ], XOR-swizzled

    const int blk   = blockIdx.x;
    const int per_b = 16 * split;
    const int b     = blk / per_b;
    const int rem   = blk - b * per_b;
    const int itile = rem / split;
    const int sp    = rem - itile * split;
    const int tid   = threadIdx.x;
    const int wave  = tid >> 6;                   // 0..7
    const int lane  = tid & 63;
    const int l32   = lane & 31;
    const int hi    = lane >> 5;
    const int i0w   = itile * 256 + wave * 32;    // wave's first of 32 rows
    const int jcnt  = NPIX / split;
    const int jlo   = sp * jcnt;
    const int niter = jcnt / KVBLK;

    const short* Qb = (const short*)Qg + (size_t)b * NPIX * CCH;
    const char*  Gb = (const char*)(Gg + (size_t)b * NPIX * CCH);
    const char*  Kb = (const char*)(Kg + (size_t)b * CCH * NPIX);

    // Q B-frags: q[ks] -> Q[i0w+l32][16ks+8hi+t]
    short8 q[4];
    #pragma unroll
    for (int ks = 0; ks < 4; ++ks)
        q[ks] = *(const short8*)(Qb + (size_t)(i0w + l32) * CCH + ks * 16 + hi * 8);

    // hoisted per-lane LDS read bases; per-read addr = base ^ (slot<<4), slot=2ks+hi
    int gbase[2], kbase[2];
    #pragma unroll
    for (int jb = 0; jb < 2; ++jb)
        gbase[jb] = (jb * 32 + l32) * 128 + ((l32 & 7) << 4);
    #pragma unroll
    for (int cb = 0; cb < 2; ++cb)
        kbase[cb] = 8192 + (cb * 32 + l32) * 128 + ((l32 & 7) << 4);

    // hoisted per-lane staging source pointers (512 threads cover 8KB per half)
    const int srow = tid >> 3, scolb = (tid & 7) * 16;
    const char* gsrc = Gb + (size_t)(jlo + srow) * 128 + (scolb ^ ((srow & 7) << 4));
    const char* ksrc = Kb + (size_t)srow * 8192 + (size_t)jlo * 2 + (scolb ^ ((srow & 7) << 4));

    f32x16 zacc;
    #pragma unroll
    for (int r = 0; r < 16; ++r) zacc[r] = 0.f;

    f32x16 o[2];                         // [cb] O^T accumulators (32 rows x 64 ch)
    #pragma unroll
    for (int cb = 0; cb < 2; ++cb)
        #pragma unroll
        for (int r = 0; r < 16; ++r) o[cb][r] = 0.f;
    float ps = 0.f;                      // per-lane denominator partial (i = lane&31)

    auto STAGE = [&](int buf, int tt) {
        gload_lds16(gsrc + tt * (KVBLK * 128), lds[buf] + wave * 1024);
        gload_lds16(ksrc + tt * (KVBLK * 2),  lds[buf] + 8192 + wave * 1024);
    };

    STAGE(0, 0);
    __syncthreads();

    for (int t = 0; t < niter; ++t) {
        const int cur = t & 1;
        STAGE(cur ^ 1, (t + 1 < niter) ? t + 1 : 0);   // uniform (tail re-stages tile 0)
        const char* L = lds[cur];

        #pragma unroll
        for (int jb = 0; jb < 2; ++jb) {
            short8 ga[4];
            #pragma unroll
            for (int ks = 0; ks < 4; ++ks)
                ga[ks] = *(const short8*)(L + (gbase[jb] ^ ((2 * ks + hi) << 4)));

            __builtin_amdgcn_s_setprio(1);
            f32x16 acc = __builtin_amdgcn_mfma_f32_32x32x16_bf16(ga[0], q[0], zacc, 0, 0, 0);
            acc = __builtin_amdgcn_mfma_f32_32x32x16_bf16(ga[1], q[1], acc, 0, 0, 0);
            acc = __builtin_amdgcn_mfma_f32_32x32x16_bf16(ga[2], q[2], acc, 0, 0, 0);
            acc = __builtin_amdgcn_mfma_f32_32x32x16_bf16(ga[3], q[3], acc, 0, 0, 0);
            __builtin_amdgcn_s_setprio(0);

            float p[16];
            #pragma unroll
            for (int r = 0; r < 16; ++r) {
                p[r] = __builtin_amdgcn_exp2f(acc[r]);
                ps += p[r];
            }
            // pack: p[r] holds j_local=(r&3)+8*(r>>2)+4hi; PV B-frag needs
            // lane(hi) to hold j=16kk'+8hi+t. cvt_pk pairs + permlane32_swap (T12).
            short8 pf[2];
            #pragma unroll
            for (int kk = 0; kk < 2; ++kk) {
                unsigned int x0 = pack_bf16(p[8 * kk + 0], p[8 * kk + 1]);
                unsigned int x1 = pack_bf16(p[8 * kk + 2], p[8 * kk + 3]);
                unsigned int y0 = pack_bf16(p[8 * kk + 4], p[8 * kk + 5]);
                unsigned int y1 = pack_bf16(p[8 * kk + 6], p[8 * kk + 7]);
                asm("v_permlane32_swap_b32 %0, %1" : "+v"(x0), "+v"(y0));
                asm("v_permlane32_swap_b32 %0, %1" : "+v"(x1), "+v"(y1));
                union { unsigned int u[4]; short8 v; } w;
                w.u[0] = x0; w.u[1] = x1; w.u[2] = y0; w.u[3] = y1;
                pf[kk] = w.v;
            }

            // PV for this jb's two k-slices (ksg = 2jb+kk)
            __builtin_amdgcn_s_setprio(1);
            #pragma unroll
            for (int kk = 0; kk < 2; ++kk) {
                const int ksg = 2 * jb + kk;
                const short8 ka0 = *(const short8*)(L + (kbase[0] ^ ((2 * ksg + hi) << 4)));
                const short8 ka1 = *(const short8*)(L + (kbase[1] ^ ((2 * ksg + hi) << 4)));
                o[0] = __builtin_amdgcn_mfma_f32_32x32x16_bf16(ka0, pf[kk], o[0], 0, 0, 0);
                o[1] = __builtin_amdgcn_mfma_f32_32x32x16_bf16(ka1, pf[kk], o[1], 0, 0, 0);
            }
            __builtin_amdgcn_s_setprio(0);
        }
        __syncthreads();   // drains staging vmcnt + all waves done reading cur
    }

    // epilogue: O^T is channel-major -> coalesced bf16 stores
    const size_t pb = (size_t)(b * split + sp);
    #pragma unroll
    for (int cb = 0; cb < 2; ++cb)
        #pragma unroll
        for (int r = 0; r < 16; ++r) {
            const int c = cb * 32 + (r & 3) + 8 * (r >> 2) + 4 * hi;
            const int i = i0w + l32;
            Opart[(pb * CCH + c) * NPIX + i] = __float2bfloat16(o[cb][r]);
        }
    // combine hi-halves of the per-lane denominator partial
    ps += __shfl_xor(ps, 32);
    if (lane < 32)
        Lpart[pb * NPIX + i0w + l32] = ps;
}

// ---------------------------------------------------------------------------
// Kernel 3: combine split partials: out[b][c][i] = sum_sp O / sum_sp L + x
// (Opart bf16, channel-major like x/out: no transpose needed.)
// ---------------------------------------------------------------------------
__global__ __launch_bounds__(256) void combine_kernel(
    const __hip_bfloat16* __restrict__ Opart, const float* __restrict__ Lpart,
    const float* __restrict__ x, float* __restrict__ out, int split)
{
    const int b = blockIdx.x >> 6, c = blockIdx.x & 63;
    #pragma unroll
    for (int chunk = 0; chunk < 2; ++chunk) {
        const int i = chunk * 2048 + threadIdx.x * 8;
        float acc[8] = {0,0,0,0,0,0,0,0};
        float Ls[8]  = {0,0,0,0,0,0,0,0};
        for (int s = 0; s < split; ++s) {
            const size_t pb = (size_t)(b * split + s);
            const short8 ov = *(const short8*)((const short*)Opart + (pb * CCH + c) * NPIX + i);
            const f32x4 l0 = *(const f32x4*)&Lpart[pb * NPIX + i];
            const f32x4 l1 = *(const f32x4*)&Lpart[pb * NPIX + i + 4];
            #pragma unroll
            for (int t = 0; t < 8; ++t) {
                union { unsigned int u; float f; } cv;
                cv.u = ((unsigned int)(unsigned short)ov[t]) << 16;
                acc[t] += cv.f;
                Ls[t]  += (t < 4) ? l0[t] : l1[t - 4];
            }
        }
        const size_t idx = ((size_t)b * CCH + c) * NPIX + i;
        const f32x4 xv0 = *(const f32x4*)&x[idx];
        const f32x4 xv1 = *(const f32x4*)&x[idx + 4];
        f32x4 r0, r1;
        #pragma unroll
        for (int t = 0; t < 4; ++t) {
            r0[t] = acc[t] / Ls[t] + xv0[t];
            r1[t] = acc[t + 4] / Ls[t + 4] + xv1[t];
        }
        *(f32x4*)&out[idx]     = r0;
        *(f32x4*)&out[idx + 4] = r1;
    }
}

extern "C" void kernel_launch(void* const* d_in, const int* in_sizes, int n_in,
                              void* d_out, int out_size, void* d_ws, size_t ws_size,
                              hipStream_t stream) {
    const float* x  = (const float*)d_in[0];
    const float* W1 = (const float*)d_in[1];
    const float* b1 = (const float*)d_in[2];
    const float* W2 = (const float*)d_in[3];
    const float* b2 = (const float*)d_in[4];
    const float* W3 = (const float*)d_in[5];
    const float* b3 = (const float*)d_in[6];
    float* out = (float*)d_out;

    char* ws = (char*)d_ws;
    const size_t planeB = (size_t)NB * NPIX * CCH * sizeof(__hip_bfloat16); // 4 MB
    __hip_bfloat16* Q = (__hip_bfloat16*)(ws);
    __hip_bfloat16* G = (__hip_bfloat16*)(ws + planeB);
    __hip_bfloat16* K = (__hip_bfloat16*)(ws + 2 * planeB);

    const size_t base   = 3 * planeB;                               // 12 MB
    const size_t oPlane = planeB;                                   // 4 MB per split (bf16)
    const size_t lPlane = (size_t)NB * NPIX * sizeof(float);        // 128 KB per split

    // prefer split=8 (1024 blocks); fall back if ws is tight
    int split = 8;
    while (split > 1 && base + (size_t)split * (oPlane + lPlane) > ws_size)
        split >>= 1;

    __hip_bfloat16* Opart = (__hip_bfloat16*)(ws + base);
    float* Lpart = (float*)(ws + base + (size_t)split * oPlane);

    proj_kernel<<<dim3(NB * 64 * 3), dim3(256), 0, stream>>>(x, W1, b1, W2, b2, W3, b3, Q, G, K);
    attn_kernel<<<dim3(NB * 16 * split), dim3(512), 0, stream>>>(Q, G, K, Opart, Lpart, split);
    combine_kernel<<<dim3(NB * CCH), dim3(256), 0, stream>>>(Opart, Lpart, x, out, split);
}